// Round 11
// baseline (358.469 us; speedup 1.0000x reference)
//
#include <hip/hip_runtime.h>
#include <cstddef>

// Swin shifted-window attention, fused per-window MFMA kernel, fp16, v11.
// = v10 structure + v9's (correctness-verified) register dataflow, spill-safe:
//  - LDS 32768 B (KT 12K | VT 12K | PP 8K) -> 5 blocks/CU, launch_bounds(256,5)
//  - phase 1b (K/V staging) FIRST, then the only barrier, then q-projection
//    (wave-private, never crosses the barrier) -> barrier waits only on K/V
//  - q D-frags -> qa B-frags via ds_bpermute (QT eliminated)
//  - ao D-frags -> obw B-frags via ds_bpermute (no LDS round-trip)
//  - no runtime-indexed vector arrays; ring-2 weight prefetch; bias as MFMA C.

typedef _Float16 half8 __attribute__((ext_vector_type(8)));
typedef float f4v __attribute__((ext_vector_type(4)));
typedef unsigned short u16;
typedef unsigned int u32;

#define MFMA(A, B, C) __builtin_amdgcn_mfma_f32_16x16x32_f16((A), (B), (C), 0, 0, 0)
#define BPERM(addr, val) __builtin_amdgcn_ds_bpermute((addr), (val))

__device__ inline u16 f16b(float f) { return __builtin_bit_cast(u16, (_Float16)f); }
__device__ inline u32 pkrtz(float a, float b) {
    return __builtin_bit_cast(u32, __builtin_amdgcn_cvt_pkrtz(a, b));
}
// fragment-LDS unit swizzle: byte = frag*1024 + unit*16 + elem*2
__device__ inline int SWU(int a, int kg) {
    return (((a ^ (kg << 1) ^ ((a & 8) >> 1)) & 15) | (kg << 4));
}

// ---- prep: weights -> f16 (q pre-scaled by SCALE*log2e); bias -> C-fragment layout ----
__global__ void prep_kernel(const float* __restrict__ wqkv, const float* __restrict__ wout,
                            const float* __restrict__ btab, const int* __restrict__ ridx,
                            const float* __restrict__ bqkv,
                            u16* __restrict__ wq16, u16* __restrict__ wo16,
                            float* __restrict__ bmf, float* __restrict__ bqs)
{
    const int i = blockIdx.x * 256 + threadIdx.x;
    const float LOG2E = 1.4426950408889634f;
    const float QS = 0.17677669529663688f * LOG2E;   // 1/sqrt(32) * log2(e)
    if (i < 27648) {
        float f = wqkv[i];
        if (i < 9216) f *= QS;                 // q rows
        wq16[i] = f16b(f);
    } else if (i < 36864) {
        wo16[i - 27648] = f16b(wout[i - 27648]);
    } else if (i < 49152) {
        // bmf: C-operand fragments, j = ((h*4+ut)*4+w)*256 + lane*4 + i
        // lane (l15,lg), reg i holds D[u = ut*16+lg*4+i][t = w*16+l15]
        const int j  = i - 36864;
        const int fi = j & 3, ln = (j >> 2) & 63, fw = (j >> 8) & 3;
        const int fut = (j >> 10) & 3, fh = j >> 12;
        const int u  = fut * 16 + (ln >> 4) * 4 + fi;
        const int tt = fw * 16 + (ln & 15);
        float v;
        if (u >= 49)       v = -1e30f;                                  // mask baked in
        else if (tt >= 49) v = 0.f;                                     // junk rows, don't care
        else               v = btab[ridx[tt * 49 + u] * 3 + fh] * LOG2E;
        bmf[j] = v;
    } else if (i < 49440) {
        const int j = i - 49152;
        float f = bqkv[j];
        if (j < 96) f *= QS;
        bqs[j] = f;
    }
}

// ---- main fused kernel ----
__global__ __launch_bounds__(256, 5)
void swin_kernel(const float* __restrict__ x,
                 const u16* __restrict__ wq16,
                 const u16* __restrict__ wo16,
                 const float* __restrict__ bqs,
                 const float* __restrict__ bout,
                 const float* __restrict__ bmf,
                 float* __restrict__ out)
{
    // LDS map (32768 B exactly -> 5 blocks/CU):
    //   KT [0,12288)       kt frag(((n-6)>>1)*4 + m)   (shared, read-only after barrier)
    //   VT [12288,24576)   vt frag((hh*2+nd)*2 + ku)   (shared, read-only after barrier)
    //   PP [24576,32768)   P pool, 2 KB/wave (wave-private: ku0 at +0, ku1 at +1024)
    __shared__ __attribute__((aligned(16))) char smem[32768];
    constexpr int KT = 0, VT = 12288, PP = 24576;

    const int tid  = threadIdx.x;
    const int w    = tid >> 6;        // wave 0..3 = token m-tile owned
    const int lane = tid & 63;
    const int l15  = lane & 15;
    const int lg   = lane >> 4;       // 0..3

    const int blk = blockIdx.x;
    const int bb  = blk >> 10;
    const int wi7 = ((blk >> 5) & 31) * 7;
    const int wj7 = (blk & 31) * 7;

    const int swbase = SWU(l15, lg) * 16;
    const int elb    = (lg & 1) * 8;          // byte offset of elem block within unit

    // pixel offset (floats) for token t of this window, shifted
    auto pixoff = [&](int t) -> size_t {
        const int tr = t / 7, tc = t - tr * 7;
        int r = wi7 + tr + 3; if (r >= 224) r -= 224;
        int c = wj7 + tc + 3; if (c >= 224) c -= 224;
        return ((size_t)((bb * 224 + r) * 224 + c)) * 96;
    };

    // ---- X^T B-frags (dual-use as A-frags for V path): all 4 m-tiles + own copy ----
    half8 xb[4][3];
    #pragma unroll
    for (int m = 0; m < 4; ++m) {
        const float* xrow = x + pixoff(m * 16 + l15) + lg * 8;
        #pragma unroll
        for (int ks = 0; ks < 3; ++ks) {
            const float4 f0 = *(const float4*)(xrow + ks * 32);
            const float4 f1 = *(const float4*)(xrow + ks * 32 + 4);
            uint4 pk;
            pk.x = pkrtz(f0.x, f0.y); pk.y = pkrtz(f0.z, f0.w);
            pk.z = pkrtz(f1.x, f1.y); pk.w = pkrtz(f1.z, f1.w);
            xb[m][ks] = __builtin_bit_cast(half8, pk);
        }
    }
    half8 xown[3];        // own m-tile (= xb[w], reloaded to avoid runtime indexing)
    {
        const float* xrow = x + pixoff(w * 16 + l15) + lg * 8;
        #pragma unroll
        for (int ks = 0; ks < 3; ++ks) {
            const float4 f0 = *(const float4*)(xrow + ks * 32);
            const float4 f1 = *(const float4*)(xrow + ks * 32 + 4);
            uint4 pk;
            pk.x = pkrtz(f0.x, f0.y); pk.y = pkrtz(f0.z, f0.w);
            pk.z = pkrtz(f1.x, f1.y); pk.w = pkrtz(f1.z, f1.w);
            xown[ks] = __builtin_bit_cast(half8, pk);
        }
    }

    const u16* wbase = wq16 + (size_t)l15 * 96 + lg * 8;

    // ============ Phase 1b: K/V staging (wave owns n in {6+w, 10+w, 14+w}) ============
    {
        half8 wcur[3], wnxt[3];
        {
            const u16* p = wbase + (size_t)(6 + w) * 1536;
            wcur[0] = *(const half8*)(p); wcur[1] = *(const half8*)(p + 32); wcur[2] = *(const half8*)(p + 64);
        }
        #pragma unroll
        for (int i = 0; i < 3; ++i) {
            const int n = 6 + w + 4 * i;      // wave-uniform
            if (i < 2) {
                const u16* p = wbase + (size_t)(n + 4) * 1536;
                wnxt[0] = *(const half8*)(p); wnxt[1] = *(const half8*)(p + 32); wnxt[2] = *(const half8*)(p + 64);
            }
            if (n < 12) {                     // k: transposed (A=W, B=X^T)
                const float4 b4 = *(const float4*)(bqs + n * 16 + lg * 4);
                const int kg  = ((n & 1) << 1) + (lg >> 1);
                const int fr0 = KT + ((((n - 6) >> 1) * 4) << 10);
                #pragma unroll
                for (int m = 0; m < 4; ++m) {
                    f4v acc = { b4.x, b4.y, b4.z, b4.w };
                    acc = MFMA(wcur[0], xb[m][0], acc);
                    acc = MFMA(wcur[1], xb[m][1], acc);
                    acc = MFMA(wcur[2], xb[m][2], acc);
                    uint2 pv;
                    pv.x = pkrtz(acc[0], acc[1]);
                    pv.y = pkrtz(acc[2], acc[3]);
                    *(uint2*)(smem + fr0 + (m << 10) + SWU(l15, kg) * 16 + elb) = pv;
                }
            } else {                          // v: direct (A=X, B=W^T)
                const float bv = bqs[n * 16 + l15];
                const int hh = (n - 12) >> 1, nd = n & 1;
                const int fr0 = VT + (((hh * 2 + nd) * 2) << 10);
                #pragma unroll
                for (int m = 0; m < 4; ++m) {
                    f4v acc = { bv, bv, bv, bv };
                    acc = MFMA(xb[m][0], wcur[0], acc);
                    acc = MFMA(xb[m][1], wcur[1], acc);
                    acc = MFMA(xb[m][2], wcur[2], acc);
                    uint2 pv;
                    pv.x = pkrtz(acc[0], acc[1]);
                    pv.y = pkrtz(acc[2], acc[3]);
                    const int kg = ((m & 1) << 1) + (lg >> 1);
                    *(uint2*)(smem + fr0 + ((m >> 1) << 10) + SWU(l15, kg) * 16 + elb) = pv;
                }
            }
            if (i < 2) { wcur[0] = wnxt[0]; wcur[1] = wnxt[1]; wcur[2] = wnxt[2]; }
        }
    }
    __syncthreads();      // the ONLY barrier (waits only on K/V staging)

    // ============ Phase 1a: q projection for own m-tile (post-barrier, wave-private) ============
    u32 qd[12];                               // D-words: qd[2n+word], n = 0..5
    {
        half8 wcur[3], wnxt[3];
        {
            const u16* p = wbase;
            wcur[0] = *(const half8*)(p); wcur[1] = *(const half8*)(p + 32); wcur[2] = *(const half8*)(p + 64);
        }
        #pragma unroll
        for (int n = 0; n < 6; ++n) {
            if (n < 5) {
                const u16* p = wbase + (size_t)(n + 1) * 1536;
                wnxt[0] = *(const half8*)(p); wnxt[1] = *(const half8*)(p + 32); wnxt[2] = *(const half8*)(p + 64);
            }
            const float4 b4 = *(const float4*)(bqs + n * 16 + lg * 4);
            f4v acc = { b4.x, b4.y, b4.z, b4.w };
            acc = MFMA(wcur[0], xown[0], acc);
            acc = MFMA(wcur[1], xown[1], acc);
            acc = MFMA(wcur[2], xown[2], acc);
            qd[2 * n]     = pkrtz(acc[0], acc[1]);
            qd[2 * n + 1] = pkrtz(acc[2], acc[3]);
            if (n < 5) { wcur[0] = wnxt[0]; wcur[1] = wnxt[1]; wcur[2] = wnxt[2]; }
        }
    }

    // ---- qa[3] B-frags from qd via bpermute (verified v9 transpose) ----
    const int sl0 = (l15 + 16 * ((lg & 1) * 2)) << 2;
    const int sl1 = sl0 + (16 << 2);
    const bool hi = (lg >= 2);
    half8 qa[3];
    #pragma unroll
    for (int h = 0; h < 3; ++h) {
        const int A0 = BPERM(sl0, (int)qd[4 * h + 0]), B0 = BPERM(sl0, (int)qd[4 * h + 2]);
        const int A1 = BPERM(sl0, (int)qd[4 * h + 1]), B1 = BPERM(sl0, (int)qd[4 * h + 3]);
        const int A2 = BPERM(sl1, (int)qd[4 * h + 0]), B2 = BPERM(sl1, (int)qd[4 * h + 2]);
        const int A3 = BPERM(sl1, (int)qd[4 * h + 1]), B3 = BPERM(sl1, (int)qd[4 * h + 3]);
        uint4 qw;
        qw.x = (u32)(hi ? B0 : A0);
        qw.y = (u32)(hi ? B1 : A1);
        qw.z = (u32)(hi ? B2 : A2);
        qw.w = (u32)(hi ? B3 : A3);
        qa[h] = __builtin_bit_cast(half8, qw);
    }

    // ============ Phase 2: attention (exp2 domain), zero barriers ============
    uint4 obw[3];         // ob B-frags (phase-3 operands)
    {
        const int ppb = PP + (w << 11);
        half8 kb[4]; f4v bC[4];
        #pragma unroll
        for (int ut = 0; ut < 4; ++ut)
            kb[ut] = *(const half8*)(smem + KT + (ut << 10) + swbase);
        {
            const float* bp = bmf + w * 256 + lane * 4;
            #pragma unroll
            for (int ut = 0; ut < 4; ++ut) bC[ut] = *(const f4v*)(bp + ut * 1024);
        }
        #pragma unroll
        for (int h = 0; h < 3; ++h) {
            // scores (bias + u>=49 mask folded into C operand)
            f4v s[4];
            #pragma unroll
            for (int ut = 0; ut < 4; ++ut)
                s[ut] = MFMA(kb[ut], qa[h], bC[ut]);
            // prefetch next head's kb + bC (current ones consumed)
            if (h < 2) {
                #pragma unroll
                for (int ut = 0; ut < 4; ++ut)
                    kb[ut] = *(const half8*)(smem + KT + (((h + 1) * 4 + ut) << 10) + swbase);
                const float* bp = bmf + (h + 1) * 4096 + w * 256 + lane * 4;
                #pragma unroll
                for (int ut = 0; ut < 4; ++ut) bC[ut] = *(const f4v*)(bp + ut * 1024);
            }
            // V-frag reads issued EARLY: DS latency hides under softmax VALU
            const half8 vb00 = *(const half8*)(smem + VT + (((h * 2 + 0) * 2 + 0) << 10) + swbase);
            const half8 vb01 = *(const half8*)(smem + VT + (((h * 2 + 0) * 2 + 1) << 10) + swbase);
            const half8 vb10 = *(const half8*)(smem + VT + (((h * 2 + 1) * 2 + 0) << 10) + swbase);
            const half8 vb11 = *(const half8*)(smem + VT + (((h * 2 + 1) * 2 + 1) << 10) + swbase);
            // softmax over row t (16 vals/lane x 4 lane-groups, butterfly over lg)
            float mx = -1e30f;
            #pragma unroll
            for (int ut = 0; ut < 4; ++ut)
                #pragma unroll
                for (int i = 0; i < 4; ++i) mx = fmaxf(mx, s[ut][i]);
            mx = fmaxf(mx, __shfl_xor(mx, 16));
            mx = fmaxf(mx, __shfl_xor(mx, 32));
            float sm = 0.f;
            #pragma unroll
            for (int ut = 0; ut < 4; ++ut)
                #pragma unroll
                for (int i = 0; i < 4; ++i) {
                    const float e = exp2f(s[ut][i] - mx);
                    s[ut][i] = e; sm += e;
                }
            sm += __shfl_xor(sm, 16);
            sm += __shfl_xor(sm, 32);
            const float inv = 1.f / sm;
            // P -> wave-private pool (b64 swizzled writes)
            #pragma unroll
            for (int ut = 0; ut < 4; ++ut) {
                uint2 pv;
                pv.x = pkrtz(s[ut][0] * inv, s[ut][1] * inv);
                pv.y = pkrtz(s[ut][2] * inv, s[ut][3] * inv);
                const int kg = (ut & 1) * 2 + (lg >> 1);
                const int base = (ut < 2) ? ppb : (ppb + 1024);
                *(uint2*)(smem + base + SWU(l15, kg) * 16 + elb) = pv;
            }
            // P readback (in-order DS per wave) + PV
            const half8 p0 = *(const half8*)(smem + ppb + swbase);
            const half8 p1 = *(const half8*)(smem + ppb + 1024 + swbase);
            u32 aw[4];
            #pragma unroll
            for (int nd = 0; nd < 2; ++nd) {
                f4v o = {0.f, 0.f, 0.f, 0.f};
                o = MFMA(nd ? vb10 : vb00, p0, o);
                o = MFMA(nd ? vb11 : vb01, p1, o);
                aw[nd * 2]     = pkrtz(o[0], o[1]);
                aw[nd * 2 + 1] = pkrtz(o[2], o[3]);
            }
            // ao D-frag -> ob B-frag via bpermute (no LDS round-trip)
            {
                const int A0 = BPERM(sl0, (int)aw[0]), B0 = BPERM(sl0, (int)aw[2]);
                const int A1 = BPERM(sl0, (int)aw[1]), B1 = BPERM(sl0, (int)aw[3]);
                const int A2 = BPERM(sl1, (int)aw[0]), B2 = BPERM(sl1, (int)aw[2]);
                const int A3 = BPERM(sl1, (int)aw[1]), B3 = BPERM(sl1, (int)aw[3]);
                obw[h].x = (u32)(hi ? B0 : A0);
                obw[h].y = (u32)(hi ? B1 : A1);
                obw[h].z = (u32)(hi ? B2 : A2);
                obw[h].w = (u32)(hi ? B3 : A3);
            }
        }
    }

    // ============ Phase 3: transposed out-proj (Wo * O^T), ob from regs, dbuf weights ============
    {
        const half8 ob0 = __builtin_bit_cast(half8, obw[0]);
        const half8 ob1 = __builtin_bit_cast(half8, obw[1]);
        const half8 ob2 = __builtin_bit_cast(half8, obw[2]);
        const int t = w * 16 + l15;
        float* obase = nullptr;
        if (t < 49) obase = out + pixoff(t);
        half8 wA0, wA1, wA2, wB0, wB1, wB2;
        float4 boA, boB;
        {
            const u16* wp = wo16 + (size_t)l15 * 96 + lg * 8;   // nn = 0
            wA0 = *(const half8*)(wp);
            wA1 = *(const half8*)(wp + 32);
            wA2 = *(const half8*)(wp + 64);
            boA = *(const float4*)(bout + lg * 4);
        }
        #pragma unroll
        for (int nn = 0; nn < 6; ++nn) {
            if (nn < 5) {
                const u16* wp = wo16 + (size_t)((nn + 1) * 16 + l15) * 96 + lg * 8;
                wB0 = *(const half8*)(wp);
                wB1 = *(const half8*)(wp + 32);
                wB2 = *(const half8*)(wp + 64);
                boB = *(const float4*)(bout + (nn + 1) * 16 + lg * 4);
            }
            f4v acc = { boA.x, boA.y, boA.z, boA.w };           // bias as C-operand
            acc = MFMA(wA0, ob0, acc);
            acc = MFMA(wA1, ob1, acc);
            acc = MFMA(wA2, ob2, acc);
            if (obase) {
                float4 res;
                res.x = acc[0]; res.y = acc[1]; res.z = acc[2]; res.w = acc[3];
                *(float4*)(obase + nn * 16 + lg * 4) = res;
            }
            if (nn < 5) { wA0 = wB0; wA1 = wB1; wA2 = wB2; boA = boB; }
        }
    }
}

extern "C" void kernel_launch(void* const* d_in, const int* in_sizes, int n_in,
                              void* d_out, int out_size, void* d_ws, size_t ws_size,
                              hipStream_t stream) {
    const float* x          = (const float*)d_in[0];
    const float* w_qkv      = (const float*)d_in[1];
    const float* b_qkv      = (const float*)d_in[2];
    const float* w_out      = (const float*)d_in[3];
    const float* b_out      = (const float*)d_in[4];
    const float* bias_table = (const float*)d_in[5];
    const int*   rel_index  = (const int*)d_in[6];
    float* outp = (float*)d_out;

    // d_ws: wq16[27648]u16 | wo16[9216]u16 | bmf[3*4*4*256]f32 | bqs[288]f32  (124032 B)
    u16* wq16 = (u16*)d_ws;
    u16* wo16 = wq16 + 27648;
    float* bmf = (float*)((char*)d_ws + 73728);
    float* bqs = (float*)((char*)d_ws + 122880);

    prep_kernel<<<dim3(194), dim3(256), 0, stream>>>(
        w_qkv, w_out, bias_table, rel_index, b_qkv, wq16, wo16, bmf, bqs);
    swin_kernel<<<dim3(8192), dim3(256), 0, stream>>>(
        x, wq16, wo16, bqs, b_out, bmf, outp);
}

// Round 12
// 288.992 us; speedup vs baseline: 1.2404x; 1.2404x over previous
//
#include <hip/hip_runtime.h>
#include <cstddef>

// Swin shifted-window attention, fused per-window MFMA kernel, fp16, v12.
// = v11's (twice correctness-verified) 32KB/5-block dataflow, register-budgeted
//   to actually fit the (256,5) VGPR cap (~102) without spilling:
//   - phase 1b K/V staging in TWO m-passes: only 2 m-tiles of X live (24 regs)
//     + ring-2 weights (24); weights re-read per pass (L2-hot, cheap)
//   - phase 2: no cross-head prefetch; kb/bC JIT-loaded per head; V reads
//     placed after P-write (not held across softmax)
//   - q/ao transposes via ds_bpermute (no QT LDS), P via 2KB/wave LDS pool
// LDS = KT 12K | VT 12K | PP 8K = 32768 B -> 5 blocks/CU (20 waves/CU).
// One barrier total.

typedef _Float16 half8 __attribute__((ext_vector_type(8)));
typedef float f4v __attribute__((ext_vector_type(4)));
typedef unsigned short u16;
typedef unsigned int u32;

#define MFMA(A, B, C) __builtin_amdgcn_mfma_f32_16x16x32_f16((A), (B), (C), 0, 0, 0)
#define BPERM(addr, val) __builtin_amdgcn_ds_bpermute((addr), (val))

__device__ inline u16 f16b(float f) { return __builtin_bit_cast(u16, (_Float16)f); }
__device__ inline u32 pkrtz(float a, float b) {
    return __builtin_bit_cast(u32, __builtin_amdgcn_cvt_pkrtz(a, b));
}
// fragment-LDS unit swizzle: byte = frag*1024 + unit*16 + elem*2
__device__ inline int SWU(int a, int kg) {
    return (((a ^ (kg << 1) ^ ((a & 8) >> 1)) & 15) | (kg << 4));
}

// ---- prep: weights -> f16 (q pre-scaled by SCALE*log2e); bias -> C-fragment layout ----
__global__ void prep_kernel(const float* __restrict__ wqkv, const float* __restrict__ wout,
                            const float* __restrict__ btab, const int* __restrict__ ridx,
                            const float* __restrict__ bqkv,
                            u16* __restrict__ wq16, u16* __restrict__ wo16,
                            float* __restrict__ bmf, float* __restrict__ bqs)
{
    const int i = blockIdx.x * 256 + threadIdx.x;
    const float LOG2E = 1.4426950408889634f;
    const float QS = 0.17677669529663688f * LOG2E;   // 1/sqrt(32) * log2(e)
    if (i < 27648) {
        float f = wqkv[i];
        if (i < 9216) f *= QS;                 // q rows
        wq16[i] = f16b(f);
    } else if (i < 36864) {
        wo16[i - 27648] = f16b(wout[i - 27648]);
    } else if (i < 49152) {
        // bmf: C-operand fragments, j = ((h*4+ut)*4+w)*256 + lane*4 + i
        // lane (l15,lg), reg i holds D[u = ut*16+lg*4+i][t = w*16+l15]
        const int j  = i - 36864;
        const int fi = j & 3, ln = (j >> 2) & 63, fw = (j >> 8) & 3;
        const int fut = (j >> 10) & 3, fh = j >> 12;
        const int u  = fut * 16 + (ln >> 4) * 4 + fi;
        const int tt = fw * 16 + (ln & 15);
        float v;
        if (u >= 49)       v = -1e30f;                                  // mask baked in
        else if (tt >= 49) v = 0.f;                                     // junk rows, don't care
        else               v = btab[ridx[tt * 49 + u] * 3 + fh] * LOG2E;
        bmf[j] = v;
    } else if (i < 49440) {
        const int j = i - 49152;
        float f = bqkv[j];
        if (j < 96) f *= QS;
        bqs[j] = f;
    }
}

// ---- main fused kernel ----
__global__ __launch_bounds__(256, 5)
void swin_kernel(const float* __restrict__ x,
                 const u16* __restrict__ wq16,
                 const u16* __restrict__ wo16,
                 const float* __restrict__ bqs,
                 const float* __restrict__ bout,
                 const float* __restrict__ bmf,
                 float* __restrict__ out)
{
    // LDS map (32768 B exactly -> 5 blocks/CU):
    //   KT [0,12288)       kt frag(h*4 + ut)          (shared, read-only after barrier)
    //   VT [12288,24576)   vt frag((hh*2+nd)*2 + ku)  (shared, read-only after barrier)
    //   PP [24576,32768)   P pool, 2 KB/wave (wave-private: ku0 at +0, ku1 at +1024)
    __shared__ __attribute__((aligned(16))) char smem[32768];
    constexpr int KT = 0, VT = 12288, PP = 24576;

    const int tid  = threadIdx.x;
    const int w    = tid >> 6;        // wave 0..3 = token m-tile owned
    const int lane = tid & 63;
    const int l15  = lane & 15;
    const int lg   = lane >> 4;       // 0..3

    const int blk = blockIdx.x;
    const int bb  = blk >> 10;
    const int wi7 = ((blk >> 5) & 31) * 7;
    const int wj7 = (blk & 31) * 7;

    const int swbase = SWU(l15, lg) * 16;
    const int elb    = (lg & 1) * 8;          // byte offset of elem block within unit

    // pixel offset (floats) for token t of this window, shifted
    auto pixoff = [&](int t) -> size_t {
        const int tr = t / 7, tc = t - tr * 7;
        int r = wi7 + tr + 3; if (r >= 224) r -= 224;
        int c = wj7 + tc + 3; if (c >= 224) c -= 224;
        return ((size_t)((bb * 224 + r) * 224 + c)) * 96;
    };
    // load X^T B-frag (3 half8) for token row t, k-chunk lg*8
    auto loadxb = [&](int t, half8* dst) {
        const float* xrow = x + pixoff(t) + lg * 8;
        #pragma unroll
        for (int ks = 0; ks < 3; ++ks) {
            const float4 f0 = *(const float4*)(xrow + ks * 32);
            const float4 f1 = *(const float4*)(xrow + ks * 32 + 4);
            uint4 pk;
            pk.x = pkrtz(f0.x, f0.y); pk.y = pkrtz(f0.z, f0.w);
            pk.z = pkrtz(f1.x, f1.y); pk.w = pkrtz(f1.z, f1.w);
            dst[ks] = __builtin_bit_cast(half8, pk);
        }
    };

    const u16* wbase = wq16 + (size_t)l15 * 96 + lg * 8;

    // ============ Phase 1b: K/V staging, TWO m-passes (2 m-tiles of X live) ============
    #pragma unroll
    for (int mp = 0; mp < 2; ++mp) {
        half8 xbA[3], xbB[3];                 // m = mp*2, mp*2+1
        loadxb(mp * 32 + l15, xbA);
        loadxb(mp * 32 + 16 + l15, xbB);
        half8 wcur[3], wnxt[3];
        {
            const u16* p = wbase + (size_t)(6 + w) * 1536;
            wcur[0] = *(const half8*)(p); wcur[1] = *(const half8*)(p + 32); wcur[2] = *(const half8*)(p + 64);
        }
        #pragma unroll
        for (int i = 0; i < 3; ++i) {
            const int n = 6 + w + 4 * i;      // wave-uniform
            if (i < 2) {
                const u16* p = wbase + (size_t)(n + 4) * 1536;
                wnxt[0] = *(const half8*)(p); wnxt[1] = *(const half8*)(p + 32); wnxt[2] = *(const half8*)(p + 64);
            }
            if (n < 12) {                     // k: transposed (A=W, B=X^T)
                const float4 b4 = *(const float4*)(bqs + n * 16 + lg * 4);
                const int kg  = ((n & 1) << 1) + (lg >> 1);
                const int fr0 = KT + ((((n - 6) >> 1) * 4) << 10);
                f4v accA = { b4.x, b4.y, b4.z, b4.w };
                accA = MFMA(wcur[0], xbA[0], accA);
                accA = MFMA(wcur[1], xbA[1], accA);
                accA = MFMA(wcur[2], xbA[2], accA);
                uint2 pvA;
                pvA.x = pkrtz(accA[0], accA[1]);
                pvA.y = pkrtz(accA[2], accA[3]);
                *(uint2*)(smem + fr0 + ((mp * 2) << 10) + SWU(l15, kg) * 16 + elb) = pvA;
                f4v accB = { b4.x, b4.y, b4.z, b4.w };
                accB = MFMA(wcur[0], xbB[0], accB);
                accB = MFMA(wcur[1], xbB[1], accB);
                accB = MFMA(wcur[2], xbB[2], accB);
                uint2 pvB;
                pvB.x = pkrtz(accB[0], accB[1]);
                pvB.y = pkrtz(accB[2], accB[3]);
                *(uint2*)(smem + fr0 + ((mp * 2 + 1) << 10) + SWU(l15, kg) * 16 + elb) = pvB;
            } else {                          // v: direct (A=X, B=W^T)
                const float bv = bqs[n * 16 + l15];
                const int hh = (n - 12) >> 1, nd = n & 1;
                const int fr0 = VT + ((((hh * 2 + nd) * 2) + mp) << 10);
                f4v accA = { bv, bv, bv, bv };
                accA = MFMA(xbA[0], wcur[0], accA);
                accA = MFMA(xbA[1], wcur[1], accA);
                accA = MFMA(xbA[2], wcur[2], accA);
                uint2 pvA;
                pvA.x = pkrtz(accA[0], accA[1]);
                pvA.y = pkrtz(accA[2], accA[3]);
                *(uint2*)(smem + fr0 + SWU(l15, lg >> 1) * 16 + elb) = pvA;        // m even: kg = lg>>1
                f4v accB = { bv, bv, bv, bv };
                accB = MFMA(xbB[0], wcur[0], accB);
                accB = MFMA(xbB[1], wcur[1], accB);
                accB = MFMA(xbB[2], wcur[2], accB);
                uint2 pvB;
                pvB.x = pkrtz(accB[0], accB[1]);
                pvB.y = pkrtz(accB[2], accB[3]);
                *(uint2*)(smem + fr0 + SWU(l15, 2 + (lg >> 1)) * 16 + elb) = pvB;  // m odd: kg = 2+(lg>>1)
            }
            if (i < 2) { wcur[0] = wnxt[0]; wcur[1] = wnxt[1]; wcur[2] = wnxt[2]; }
        }
    }
    __syncthreads();      // the ONLY barrier (waits only on K/V staging)

    // ============ Phase 1a: q projection for own m-tile (post-barrier, wave-private) ============
    u32 qd[12];                               // D-words: qd[2n+word], n = 0..5
    {
        half8 xown[3];
        loadxb(w * 16 + l15, xown);
        half8 wcur[3], wnxt[3];
        {
            const u16* p = wbase;
            wcur[0] = *(const half8*)(p); wcur[1] = *(const half8*)(p + 32); wcur[2] = *(const half8*)(p + 64);
        }
        #pragma unroll
        for (int n = 0; n < 6; ++n) {
            if (n < 5) {
                const u16* p = wbase + (size_t)(n + 1) * 1536;
                wnxt[0] = *(const half8*)(p); wnxt[1] = *(const half8*)(p + 32); wnxt[2] = *(const half8*)(p + 64);
            }
            const float4 b4 = *(const float4*)(bqs + n * 16 + lg * 4);
            f4v acc = { b4.x, b4.y, b4.z, b4.w };
            acc = MFMA(wcur[0], xown[0], acc);
            acc = MFMA(wcur[1], xown[1], acc);
            acc = MFMA(wcur[2], xown[2], acc);
            qd[2 * n]     = pkrtz(acc[0], acc[1]);
            qd[2 * n + 1] = pkrtz(acc[2], acc[3]);
            if (n < 5) { wcur[0] = wnxt[0]; wcur[1] = wnxt[1]; wcur[2] = wnxt[2]; }
        }
    }

    // ---- qa[3] B-frags from qd via bpermute (verified transpose) ----
    const int sl0 = (l15 + 16 * ((lg & 1) * 2)) << 2;
    const int sl1 = sl0 + (16 << 2);
    const bool hi = (lg >= 2);
    half8 qa0, qa1, qa2;
    #pragma unroll
    for (int h = 0; h < 3; ++h) {
        const int A0 = BPERM(sl0, (int)qd[4 * h + 0]), B0 = BPERM(sl0, (int)qd[4 * h + 2]);
        const int A1 = BPERM(sl0, (int)qd[4 * h + 1]), B1 = BPERM(sl0, (int)qd[4 * h + 3]);
        const int A2 = BPERM(sl1, (int)qd[4 * h + 0]), B2 = BPERM(sl1, (int)qd[4 * h + 2]);
        const int A3 = BPERM(sl1, (int)qd[4 * h + 1]), B3 = BPERM(sl1, (int)qd[4 * h + 3]);
        uint4 qw;
        qw.x = (u32)(hi ? B0 : A0);
        qw.y = (u32)(hi ? B1 : A1);
        qw.z = (u32)(hi ? B2 : A2);
        qw.w = (u32)(hi ? B3 : A3);
        if (h == 0) qa0 = __builtin_bit_cast(half8, qw);
        else if (h == 1) qa1 = __builtin_bit_cast(half8, qw);
        else qa2 = __builtin_bit_cast(half8, qw);
    }

    // ============ Phase 2: attention (exp2 domain), zero barriers, lean registers ============
    uint4 obw0, obw1, obw2;
    {
        const int ppb = PP + (w << 11);
        #pragma unroll
        for (int h = 0; h < 3; ++h) {
            const half8 qah = (h == 0) ? qa0 : (h == 1) ? qa1 : qa2;
            // JIT per-head loads (die at the MFMA)
            f4v s[4];
            {
                const float* bp = bmf + h * 4096 + w * 256 + lane * 4;
                #pragma unroll
                for (int ut = 0; ut < 4; ++ut) {
                    const half8 kb = *(const half8*)(smem + KT + (((h * 4 + ut)) << 10) + swbase);
                    const f4v bC = *(const f4v*)(bp + ut * 1024);
                    s[ut] = MFMA(kb, qah, bC);    // bias + u>=49 mask folded into C
                }
            }
            // softmax over row t (16 vals/lane x 4 lane-groups, butterfly over lg)
            float mx = -1e30f;
            #pragma unroll
            for (int ut = 0; ut < 4; ++ut)
                #pragma unroll
                for (int i = 0; i < 4; ++i) mx = fmaxf(mx, s[ut][i]);
            mx = fmaxf(mx, __shfl_xor(mx, 16));
            mx = fmaxf(mx, __shfl_xor(mx, 32));
            float sm = 0.f;
            #pragma unroll
            for (int ut = 0; ut < 4; ++ut)
                #pragma unroll
                for (int i = 0; i < 4; ++i) {
                    const float e = exp2f(s[ut][i] - mx);
                    s[ut][i] = e; sm += e;
                }
            sm += __shfl_xor(sm, 16);
            sm += __shfl_xor(sm, 32);
            const float inv = 1.f / sm;
            // P -> wave-private pool (b64 swizzled writes)
            #pragma unroll
            for (int ut = 0; ut < 4; ++ut) {
                uint2 pv;
                pv.x = pkrtz(s[ut][0] * inv, s[ut][1] * inv);
                pv.y = pkrtz(s[ut][2] * inv, s[ut][3] * inv);
                const int kg = (ut & 1) * 2 + (lg >> 1);
                const int base = (ut < 2) ? ppb : (ppb + 1024);
                *(uint2*)(smem + base + SWU(l15, kg) * 16 + elb) = pv;
            }
            // V-frag reads + P readback (in-order DS per wave)
            const half8 vb00 = *(const half8*)(smem + VT + (((h * 2 + 0) * 2 + 0) << 10) + swbase);
            const half8 vb01 = *(const half8*)(smem + VT + (((h * 2 + 0) * 2 + 1) << 10) + swbase);
            const half8 vb10 = *(const half8*)(smem + VT + (((h * 2 + 1) * 2 + 0) << 10) + swbase);
            const half8 vb11 = *(const half8*)(smem + VT + (((h * 2 + 1) * 2 + 1) << 10) + swbase);
            const half8 p0 = *(const half8*)(smem + ppb + swbase);
            const half8 p1 = *(const half8*)(smem + ppb + 1024 + swbase);
            u32 aw[4];
            #pragma unroll
            for (int nd = 0; nd < 2; ++nd) {
                f4v o = {0.f, 0.f, 0.f, 0.f};
                o = MFMA(nd ? vb10 : vb00, p0, o);
                o = MFMA(nd ? vb11 : vb01, p1, o);
                aw[nd * 2]     = pkrtz(o[0], o[1]);
                aw[nd * 2 + 1] = pkrtz(o[2], o[3]);
            }
            // ao D-frag -> ob B-frag via bpermute (no LDS round-trip)
            {
                const int A0 = BPERM(sl0, (int)aw[0]), B0 = BPERM(sl0, (int)aw[2]);
                const int A1 = BPERM(sl0, (int)aw[1]), B1 = BPERM(sl0, (int)aw[3]);
                const int A2 = BPERM(sl1, (int)aw[0]), B2 = BPERM(sl1, (int)aw[2]);
                const int A3 = BPERM(sl1, (int)aw[1]), B3 = BPERM(sl1, (int)aw[3]);
                uint4 ow;
                ow.x = (u32)(hi ? B0 : A0);
                ow.y = (u32)(hi ? B1 : A1);
                ow.z = (u32)(hi ? B2 : A2);
                ow.w = (u32)(hi ? B3 : A3);
                if (h == 0) obw0 = ow; else if (h == 1) obw1 = ow; else obw2 = ow;
            }
        }
    }

    // ============ Phase 3: transposed out-proj (Wo * O^T), ob from regs, dbuf weights ============
    {
        const half8 ob0 = __builtin_bit_cast(half8, obw0);
        const half8 ob1 = __builtin_bit_cast(half8, obw1);
        const half8 ob2 = __builtin_bit_cast(half8, obw2);
        const int t = w * 16 + l15;
        float* obase = nullptr;
        if (t < 49) obase = out + pixoff(t);
        half8 wA0, wA1, wA2, wB0, wB1, wB2;
        float4 boA, boB;
        {
            const u16* wp = wo16 + (size_t)l15 * 96 + lg * 8;   // nn = 0
            wA0 = *(const half8*)(wp);
            wA1 = *(const half8*)(wp + 32);
            wA2 = *(const half8*)(wp + 64);
            boA = *(const float4*)(bout + lg * 4);
        }
        #pragma unroll
        for (int nn = 0; nn < 6; ++nn) {
            if (nn < 5) {
                const u16* wp = wo16 + (size_t)((nn + 1) * 16 + l15) * 96 + lg * 8;
                wB0 = *(const half8*)(wp);
                wB1 = *(const half8*)(wp + 32);
                wB2 = *(const half8*)(wp + 64);
                boB = *(const float4*)(bout + (nn + 1) * 16 + lg * 4);
            }
            f4v acc = { boA.x, boA.y, boA.z, boA.w };           // bias as C-operand
            acc = MFMA(wA0, ob0, acc);
            acc = MFMA(wA1, ob1, acc);
            acc = MFMA(wA2, ob2, acc);
            if (obase) {
                float4 res;
                res.x = acc[0]; res.y = acc[1]; res.z = acc[2]; res.w = acc[3];
                *(float4*)(obase + nn * 16 + lg * 4) = res;
            }
            if (nn < 5) { wA0 = wB0; wA1 = wB1; wA2 = wB2; boA = boB; }
        }
    }
}

extern "C" void kernel_launch(void* const* d_in, const int* in_sizes, int n_in,
                              void* d_out, int out_size, void* d_ws, size_t ws_size,
                              hipStream_t stream) {
    const float* x          = (const float*)d_in[0];
    const float* w_qkv      = (const float*)d_in[1];
    const float* b_qkv      = (const float*)d_in[2];
    const float* w_out      = (const float*)d_in[3];
    const float* b_out      = (const float*)d_in[4];
    const float* bias_table = (const float*)d_in[5];
    const int*   rel_index  = (const int*)d_in[6];
    float* outp = (float*)d_out;

    // d_ws: wq16[27648]u16 | wo16[9216]u16 | bmf[3*4*4*256]f32 | bqs[288]f32  (124032 B)
    u16* wq16 = (u16*)d_ws;
    u16* wo16 = wq16 + 27648;
    float* bmf = (float*)((char*)d_ws + 73728);
    float* bqs = (float*)((char*)d_ws + 122880);

    prep_kernel<<<dim3(194), dim3(256), 0, stream>>>(
        w_qkv, w_out, bias_table, rel_index, b_qkv, wq16, wo16, bmf, bqs);
    swin_kernel<<<dim3(8192), dim3(256), 0, stream>>>(
        x, wq16, wo16, bqs, b_out, bmf, outp);
}

// Round 13
// 271.954 us; speedup vs baseline: 1.3181x; 1.0626x over previous
//
#include <hip/hip_runtime.h>
#include <cstddef>

// Swin shifted-window attention, fused per-window MFMA kernel, fp16, v13.
// = v12's verified dataflow with the forced-spill removed:
//   - NO min-waves launch bound (plain __launch_bounds__(256)): compiler
//     allocates what it needs -> spilling is impossible by construction.
//   - P transposed via the verified 8-bpermute D->B transform (same as q/ao):
//     P LDS pool eliminated -> LDS = KT 12K + VT 12K = 24576 B, so HW can
//     co-schedule 5-6 blocks/CU if VGPR alloc lands <= 102/85.
//   - phase 1b K/V staging in two m-passes (register-lean), ring-2 weights
//   - phase 2: JIT per-head kb/bC loads; all transposes in-register
// One barrier total.

typedef _Float16 half8 __attribute__((ext_vector_type(8)));
typedef float f4v __attribute__((ext_vector_type(4)));
typedef unsigned short u16;
typedef unsigned int u32;

#define MFMA(A, B, C) __builtin_amdgcn_mfma_f32_16x16x32_f16((A), (B), (C), 0, 0, 0)
#define BPERM(addr, val) __builtin_amdgcn_ds_bpermute((addr), (val))

__device__ inline u16 f16b(float f) { return __builtin_bit_cast(u16, (_Float16)f); }
__device__ inline u32 pkrtz(float a, float b) {
    return __builtin_bit_cast(u32, __builtin_amdgcn_cvt_pkrtz(a, b));
}
// fragment-LDS unit swizzle: byte = frag*1024 + unit*16 + elem*2
__device__ inline int SWU(int a, int kg) {
    return (((a ^ (kg << 1) ^ ((a & 8) >> 1)) & 15) | (kg << 4));
}
// Verified D-frag -> A/B-frag transpose (v9/v11/v12 correctness-proven).
// In: 4 D-words (tile0 w0, tile0 w1, tile1 w0, tile1 w1), each word = 2 packed f16
// Out: one A/B-operand half8 (k = 0..31 across the two 16-row tiles)
__device__ inline half8 xpose(u32 w0, u32 w1, u32 w2, u32 w3,
                              int sl0, int sl1, bool hi) {
    const int A0 = BPERM(sl0, (int)w0), B0 = BPERM(sl0, (int)w2);
    const int A1 = BPERM(sl0, (int)w1), B1 = BPERM(sl0, (int)w3);
    const int A2 = BPERM(sl1, (int)w0), B2 = BPERM(sl1, (int)w2);
    const int A3 = BPERM(sl1, (int)w1), B3 = BPERM(sl1, (int)w3);
    uint4 r;
    r.x = (u32)(hi ? B0 : A0);
    r.y = (u32)(hi ? B1 : A1);
    r.z = (u32)(hi ? B2 : A2);
    r.w = (u32)(hi ? B3 : A3);
    return __builtin_bit_cast(half8, r);
}

// ---- prep: weights -> f16 (q pre-scaled by SCALE*log2e); bias -> C-fragment layout ----
__global__ void prep_kernel(const float* __restrict__ wqkv, const float* __restrict__ wout,
                            const float* __restrict__ btab, const int* __restrict__ ridx,
                            const float* __restrict__ bqkv,
                            u16* __restrict__ wq16, u16* __restrict__ wo16,
                            float* __restrict__ bmf, float* __restrict__ bqs)
{
    const int i = blockIdx.x * 256 + threadIdx.x;
    const float LOG2E = 1.4426950408889634f;
    const float QS = 0.17677669529663688f * LOG2E;   // 1/sqrt(32) * log2(e)
    if (i < 27648) {
        float f = wqkv[i];
        if (i < 9216) f *= QS;                 // q rows
        wq16[i] = f16b(f);
    } else if (i < 36864) {
        wo16[i - 27648] = f16b(wout[i - 27648]);
    } else if (i < 49152) {
        // bmf: C-operand fragments, j = ((h*4+ut)*4+w)*256 + lane*4 + i
        // lane (l15,lg), reg i holds D[u = ut*16+lg*4+i][t = w*16+l15]
        const int j  = i - 36864;
        const int fi = j & 3, ln = (j >> 2) & 63, fw = (j >> 8) & 3;
        const int fut = (j >> 10) & 3, fh = j >> 12;
        const int u  = fut * 16 + (ln >> 4) * 4 + fi;
        const int tt = fw * 16 + (ln & 15);
        float v;
        if (u >= 49)       v = -1e30f;                                  // mask baked in
        else if (tt >= 49) v = 0.f;                                     // junk rows, don't care
        else               v = btab[ridx[tt * 49 + u] * 3 + fh] * LOG2E;
        bmf[j] = v;
    } else if (i < 49440) {
        const int j = i - 49152;
        float f = bqkv[j];
        if (j < 96) f *= QS;
        bqs[j] = f;
    }
}

// ---- main fused kernel ----
__global__ __launch_bounds__(256)
void swin_kernel(const float* __restrict__ x,
                 const u16* __restrict__ wq16,
                 const u16* __restrict__ wo16,
                 const float* __restrict__ bqs,
                 const float* __restrict__ bout,
                 const float* __restrict__ bmf,
                 float* __restrict__ out)
{
    // LDS map (24576 B -> LDS allows 6 blocks/CU; actual residency set by VGPR alloc):
    //   KT [0,12288)       kt frag(h*4 + ut)          (shared, read-only after barrier)
    //   VT [12288,24576)   vt frag((hh*2+nd)*2 + ku)  (shared, read-only after barrier)
    __shared__ __attribute__((aligned(16))) char smem[24576];
    constexpr int KT = 0, VT = 12288;

    const int tid  = threadIdx.x;
    const int w    = tid >> 6;        // wave 0..3 = token m-tile owned
    const int lane = tid & 63;
    const int l15  = lane & 15;
    const int lg   = lane >> 4;       // 0..3

    const int blk = blockIdx.x;
    const int bb  = blk >> 10;
    const int wi7 = ((blk >> 5) & 31) * 7;
    const int wj7 = (blk & 31) * 7;

    const int swbase = SWU(l15, lg) * 16;
    const int elb    = (lg & 1) * 8;          // byte offset of elem block within unit

    // pixel offset (floats) for token t of this window, shifted
    auto pixoff = [&](int t) -> size_t {
        const int tr = t / 7, tc = t - tr * 7;
        int r = wi7 + tr + 3; if (r >= 224) r -= 224;
        int c = wj7 + tc + 3; if (c >= 224) c -= 224;
        return ((size_t)((bb * 224 + r) * 224 + c)) * 96;
    };
    // load X^T B-frag (3 half8) for token row t, k-chunk lg*8
    auto loadxb = [&](int t, half8* dst) {
        const float* xrow = x + pixoff(t) + lg * 8;
        #pragma unroll
        for (int ks = 0; ks < 3; ++ks) {
            const float4 f0 = *(const float4*)(xrow + ks * 32);
            const float4 f1 = *(const float4*)(xrow + ks * 32 + 4);
            uint4 pk;
            pk.x = pkrtz(f0.x, f0.y); pk.y = pkrtz(f0.z, f0.w);
            pk.z = pkrtz(f1.x, f1.y); pk.w = pkrtz(f1.z, f1.w);
            dst[ks] = __builtin_bit_cast(half8, pk);
        }
    };

    const u16* wbase = wq16 + (size_t)l15 * 96 + lg * 8;

    // ============ Phase 1b: K/V staging, TWO m-passes (2 m-tiles of X live) ============
    #pragma unroll
    for (int mp = 0; mp < 2; ++mp) {
        half8 xbA[3], xbB[3];                 // m = mp*2, mp*2+1
        loadxb(mp * 32 + l15, xbA);
        loadxb(mp * 32 + 16 + l15, xbB);
        half8 wcur[3], wnxt[3];
        {
            const u16* p = wbase + (size_t)(6 + w) * 1536;
            wcur[0] = *(const half8*)(p); wcur[1] = *(const half8*)(p + 32); wcur[2] = *(const half8*)(p + 64);
        }
        #pragma unroll
        for (int i = 0; i < 3; ++i) {
            const int n = 6 + w + 4 * i;      // wave-uniform
            if (i < 2) {
                const u16* p = wbase + (size_t)(n + 4) * 1536;
                wnxt[0] = *(const half8*)(p); wnxt[1] = *(const half8*)(p + 32); wnxt[2] = *(const half8*)(p + 64);
            }
            if (n < 12) {                     // k: transposed (A=W, B=X^T)
                const float4 b4 = *(const float4*)(bqs + n * 16 + lg * 4);
                const int kg  = ((n & 1) << 1) + (lg >> 1);
                const int fr0 = KT + ((((n - 6) >> 1) * 4) << 10);
                f4v accA = { b4.x, b4.y, b4.z, b4.w };
                accA = MFMA(wcur[0], xbA[0], accA);
                accA = MFMA(wcur[1], xbA[1], accA);
                accA = MFMA(wcur[2], xbA[2], accA);
                uint2 pvA;
                pvA.x = pkrtz(accA[0], accA[1]);
                pvA.y = pkrtz(accA[2], accA[3]);
                *(uint2*)(smem + fr0 + ((mp * 2) << 10) + SWU(l15, kg) * 16 + elb) = pvA;
                f4v accB = { b4.x, b4.y, b4.z, b4.w };
                accB = MFMA(wcur[0], xbB[0], accB);
                accB = MFMA(wcur[1], xbB[1], accB);
                accB = MFMA(wcur[2], xbB[2], accB);
                uint2 pvB;
                pvB.x = pkrtz(accB[0], accB[1]);
                pvB.y = pkrtz(accB[2], accB[3]);
                *(uint2*)(smem + fr0 + ((mp * 2 + 1) << 10) + SWU(l15, kg) * 16 + elb) = pvB;
            } else {                          // v: direct (A=X, B=W^T)
                const float bv = bqs[n * 16 + l15];
                const int hh = (n - 12) >> 1, nd = n & 1;
                const int fr0 = VT + ((((hh * 2 + nd) * 2) + mp) << 10);
                f4v accA = { bv, bv, bv, bv };
                accA = MFMA(xbA[0], wcur[0], accA);
                accA = MFMA(xbA[1], wcur[1], accA);
                accA = MFMA(xbA[2], wcur[2], accA);
                uint2 pvA;
                pvA.x = pkrtz(accA[0], accA[1]);
                pvA.y = pkrtz(accA[2], accA[3]);
                *(uint2*)(smem + fr0 + SWU(l15, lg >> 1) * 16 + elb) = pvA;        // m even: kg = lg>>1
                f4v accB = { bv, bv, bv, bv };
                accB = MFMA(xbB[0], wcur[0], accB);
                accB = MFMA(xbB[1], wcur[1], accB);
                accB = MFMA(xbB[2], wcur[2], accB);
                uint2 pvB;
                pvB.x = pkrtz(accB[0], accB[1]);
                pvB.y = pkrtz(accB[2], accB[3]);
                *(uint2*)(smem + fr0 + SWU(l15, 2 + (lg >> 1)) * 16 + elb) = pvB;  // m odd: kg = 2+(lg>>1)
            }
            if (i < 2) { wcur[0] = wnxt[0]; wcur[1] = wnxt[1]; wcur[2] = wnxt[2]; }
        }
    }
    __syncthreads();      // the ONLY barrier (waits only on K/V staging)

    // ============ Phase 1a: q projection for own m-tile (post-barrier, wave-private) ============
    u32 qd[12];                               // D-words: qd[2n+word], n = 0..5
    {
        half8 xown[3];
        loadxb(w * 16 + l15, xown);
        half8 wcur[3], wnxt[3];
        {
            const u16* p = wbase;
            wcur[0] = *(const half8*)(p); wcur[1] = *(const half8*)(p + 32); wcur[2] = *(const half8*)(p + 64);
        }
        #pragma unroll
        for (int n = 0; n < 6; ++n) {
            if (n < 5) {
                const u16* p = wbase + (size_t)(n + 1) * 1536;
                wnxt[0] = *(const half8*)(p); wnxt[1] = *(const half8*)(p + 32); wnxt[2] = *(const half8*)(p + 64);
            }
            const float4 b4 = *(const float4*)(bqs + n * 16 + lg * 4);
            f4v acc = { b4.x, b4.y, b4.z, b4.w };
            acc = MFMA(wcur[0], xown[0], acc);
            acc = MFMA(wcur[1], xown[1], acc);
            acc = MFMA(wcur[2], xown[2], acc);
            qd[2 * n]     = pkrtz(acc[0], acc[1]);
            qd[2 * n + 1] = pkrtz(acc[2], acc[3]);
            if (n < 5) { wcur[0] = wnxt[0]; wcur[1] = wnxt[1]; wcur[2] = wnxt[2]; }
        }
    }

    // ---- qa B-frags from qd via verified transpose ----
    const int sl0 = (l15 + 16 * ((lg & 1) * 2)) << 2;
    const int sl1 = sl0 + (16 << 2);
    const bool hi = (lg >= 2);
    const half8 qa0 = xpose(qd[0], qd[1], qd[2],  qd[3],  sl0, sl1, hi);
    const half8 qa1 = xpose(qd[4], qd[5], qd[6],  qd[7],  sl0, sl1, hi);
    const half8 qa2 = xpose(qd[8], qd[9], qd[10], qd[11], sl0, sl1, hi);

    // ============ Phase 2: attention (exp2 domain), zero barriers, all-register ============
    uint4 obw0, obw1, obw2;
    #pragma unroll
    for (int h = 0; h < 3; ++h) {
        const half8 qah = (h == 0) ? qa0 : (h == 1) ? qa1 : qa2;
        // scores: JIT per-head kb/bC loads (bias + u>=49 mask folded into C)
        f4v s[4];
        {
            const float* bp = bmf + h * 4096 + w * 256 + lane * 4;
            #pragma unroll
            for (int ut = 0; ut < 4; ++ut) {
                const half8 kb = *(const half8*)(smem + KT + ((h * 4 + ut) << 10) + swbase);
                const f4v bC = *(const f4v*)(bp + ut * 1024);
                s[ut] = MFMA(kb, qah, bC);
            }
        }
        // softmax over row t (16 vals/lane x 4 lane-groups, butterfly over lg)
        float mx = -1e30f;
        #pragma unroll
        for (int ut = 0; ut < 4; ++ut)
            #pragma unroll
            for (int i = 0; i < 4; ++i) mx = fmaxf(mx, s[ut][i]);
        mx = fmaxf(mx, __shfl_xor(mx, 16));
        mx = fmaxf(mx, __shfl_xor(mx, 32));
        float sm = 0.f;
        #pragma unroll
        for (int ut = 0; ut < 4; ++ut)
            #pragma unroll
            for (int i = 0; i < 4; ++i) {
                const float e = exp2f(s[ut][i] - mx);
                s[ut][i] = e; sm += e;
            }
        sm += __shfl_xor(sm, 16);
        sm += __shfl_xor(sm, 32);
        const float inv = 1.f / sm;
        // pack P D-words and transpose in-register to B-frags (no LDS pool)
        u32 pw0 = pkrtz(s[0][0] * inv, s[0][1] * inv);
        u32 pw1 = pkrtz(s[0][2] * inv, s[0][3] * inv);
        u32 pw2 = pkrtz(s[1][0] * inv, s[1][1] * inv);
        u32 pw3 = pkrtz(s[1][2] * inv, s[1][3] * inv);
        u32 pw4 = pkrtz(s[2][0] * inv, s[2][1] * inv);
        u32 pw5 = pkrtz(s[2][2] * inv, s[2][3] * inv);
        u32 pw6 = pkrtz(s[3][0] * inv, s[3][1] * inv);
        u32 pw7 = pkrtz(s[3][2] * inv, s[3][3] * inv);
        const half8 p0 = xpose(pw0, pw1, pw2, pw3, sl0, sl1, hi);   // k = u 0..31
        const half8 p1 = xpose(pw4, pw5, pw6, pw7, sl0, sl1, hi);   // k = u 32..63
        // V-frag reads + PV
        const half8 vb00 = *(const half8*)(smem + VT + (((h * 2 + 0) * 2 + 0) << 10) + swbase);
        const half8 vb01 = *(const half8*)(smem + VT + (((h * 2 + 0) * 2 + 1) << 10) + swbase);
        const half8 vb10 = *(const half8*)(smem + VT + (((h * 2 + 1) * 2 + 0) << 10) + swbase);
        const half8 vb11 = *(const half8*)(smem + VT + (((h * 2 + 1) * 2 + 1) << 10) + swbase);
        u32 aw[4];
        #pragma unroll
        for (int nd = 0; nd < 2; ++nd) {
            f4v o = {0.f, 0.f, 0.f, 0.f};
            o = MFMA(nd ? vb10 : vb00, p0, o);
            o = MFMA(nd ? vb11 : vb01, p1, o);
            aw[nd * 2]     = pkrtz(o[0], o[1]);
            aw[nd * 2 + 1] = pkrtz(o[2], o[3]);
        }
        // ao D-frag -> ob B-frag via verified transpose (no LDS round-trip)
        const half8 ob = xpose(aw[0], aw[1], aw[2], aw[3], sl0, sl1, hi);
        const uint4 ow = __builtin_bit_cast(uint4, ob);
        if (h == 0) obw0 = ow; else if (h == 1) obw1 = ow; else obw2 = ow;
    }

    // ============ Phase 3: transposed out-proj (Wo * O^T), ob from regs, dbuf weights ============
    {
        const half8 ob0 = __builtin_bit_cast(half8, obw0);
        const half8 ob1 = __builtin_bit_cast(half8, obw1);
        const half8 ob2 = __builtin_bit_cast(half8, obw2);
        const int t = w * 16 + l15;
        float* obase = nullptr;
        if (t < 49) obase = out + pixoff(t);
        half8 wA0, wA1, wA2, wB0, wB1, wB2;
        float4 boA, boB;
        {
            const u16* wp = wo16 + (size_t)l15 * 96 + lg * 8;   // nn = 0
            wA0 = *(const half8*)(wp);
            wA1 = *(const half8*)(wp + 32);
            wA2 = *(const half8*)(wp + 64);
            boA = *(const float4*)(bout + lg * 4);
        }
        #pragma unroll
        for (int nn = 0; nn < 6; ++nn) {
            if (nn < 5) {
                const u16* wp = wo16 + (size_t)((nn + 1) * 16 + l15) * 96 + lg * 8;
                wB0 = *(const half8*)(wp);
                wB1 = *(const half8*)(wp + 32);
                wB2 = *(const half8*)(wp + 64);
                boB = *(const float4*)(bout + (nn + 1) * 16 + lg * 4);
            }
            f4v acc = { boA.x, boA.y, boA.z, boA.w };           // bias as C-operand
            acc = MFMA(wA0, ob0, acc);
            acc = MFMA(wA1, ob1, acc);
            acc = MFMA(wA2, ob2, acc);
            if (obase) {
                float4 res;
                res.x = acc[0]; res.y = acc[1]; res.z = acc[2]; res.w = acc[3];
                *(float4*)(obase + nn * 16 + lg * 4) = res;
            }
            if (nn < 5) { wA0 = wB0; wA1 = wB1; wA2 = wB2; boA = boB; }
        }
    }
}

extern "C" void kernel_launch(void* const* d_in, const int* in_sizes, int n_in,
                              void* d_out, int out_size, void* d_ws, size_t ws_size,
                              hipStream_t stream) {
    const float* x          = (const float*)d_in[0];
    const float* w_qkv      = (const float*)d_in[1];
    const float* b_qkv      = (const float*)d_in[2];
    const float* w_out      = (const float*)d_in[3];
    const float* b_out      = (const float*)d_in[4];
    const float* bias_table = (const float*)d_in[5];
    const int*   rel_index  = (const int*)d_in[6];
    float* outp = (float*)d_out;

    // d_ws: wq16[27648]u16 | wo16[9216]u16 | bmf[3*4*4*256]f32 | bqs[288]f32  (124032 B)
    u16* wq16 = (u16*)d_ws;
    u16* wo16 = wq16 + 27648;
    float* bmf = (float*)((char*)d_ws + 73728);
    float* bqs = (float*)((char*)d_ws + 122880);

    prep_kernel<<<dim3(194), dim3(256), 0, stream>>>(
        w_qkv, w_out, bias_table, rel_index, b_qkv, wq16, wo16, bmf, bqs);
    swin_kernel<<<dim3(8192), dim3(256), 0, stream>>>(
        x, wq16, wo16, bqs, b_out, bmf, outp);
}